// Round 15
// baseline (465.630 us; speedup 1.0000x reference)
//
#include <hip/hip_runtime.h>
#include <hip/hip_bf16.h>

using bf16 = __hip_bfloat16;
using short8 = __attribute__((ext_vector_type(8))) short;
using sh4 = __attribute__((ext_vector_type(4))) short;
using f32x4 = __attribute__((ext_vector_type(4))) float;

// Pre-packed A-operand (weights) in MFMA 16x16x32 frag order, module-scope.
// L1 (div path, M-major): frag (mt,kt) at ((mt*KT + kt)*64+lane)*8.
// L2/L3: K-MAJOR 25-tile panels (M EXACT, no padding): frag (kt,mtl<25) at
//   ((kt*25+mtl)*64+lane)*8 -> one kt-panel (25 KB) contiguous for staging.
//   wp3: two 400-row halves, each its own 117-panel K-major pack.
__device__ __align__(16) bf16 g_wp1[16 * 3 * 512];        //  48 KB (M 256, KT 3)
__device__ __align__(16) bf16 g_wp2[63 * 25 * 512];       // 1.6 MB (M 400 exact)
__device__ __align__(16) bf16 g_wp3[2 * 117 * 25 * 512];  // 6.0 MB (2 x M 400)
__device__ __align__(16) bf16 g_wp4[1 * 225 * 512];       // 231 KB (M 16, KT 225)

// Compacted masked-on position lists (order-preserving -> spatial locality).
__device__ int g_list1[4225];
__device__ int g_list2[961];
__device__ int g_list3[225];
__device__ int g_cnt[3];

// ============================================================================
// Intermediate tensors stored PRE-FRAGMENTED in MFMA B-operand order (1KB
// coalesced wave reads). Cell (position, 64 batch x C ch) element offsets:
//   full subtiles cc < C/32:  el = ((cc*4 + t)*64 + q*16 + nl)*8 + j
//        where ch = cc*32 + q*8 + j, batch = t*16 + nl
//   tail (TW = C mod 32 in {8,16}), after NFULL*64 elements:
//        el = NFULL*64 + t*TW*16 + mq*128 + nl*8 + j   (ch = NFULL + mq*8 + j)
// Cell size = 64*C elements exactly -> ws layout unchanged.
// ============================================================================

// ---------------- weight packs ----------------
__global__ __launch_bounds__(256) void k_pack1(const float* __restrict__ w) {
  int el = blockIdx.x * 256 + threadIdx.x;
  if (el >= 16 * 3 * 512) return;
  int j = el & 7, lane = (el >> 3) & 63, rest = el >> 9;
  int kt = rest % 3, mt = rest / 3;
  int m = mt * 16 + (lane & 15);
  int k = kt * 32 + ((lane >> 4) * 8) + j;
  int chunk = k >> 3, c = k & 7;
  float val = 0.f;
  if (m < 200 && chunk < 9 && c < 3) val = w[((size_t)m * 3 + c) * 9 + chunk];
  g_wp1[el] = __float2bfloat16(val);
}
// K-major 25-tile pack: ti = el>>9 -> half = ti/(KT*25) (wp3 only),
// kt = (ti%(KT*25))/25, mtl = remainder, mt = half*25+mtl (M exact).
template <int CIN, int SUBT, int COUT, int KT>
__device__ __forceinline__ void pack_kmaj(const float* __restrict__ w,
                                          bf16* __restrict__ dst, int total) {
  int el = blockIdx.x * 256 + threadIdx.x;
  if (el >= total) return;
  int j = el & 7, lane = (el >> 3) & 63, ti = el >> 9;
  int half = ti / (KT * 25);
  int r2 = ti - half * (KT * 25);
  int kt = r2 / 25, mtl = r2 - kt * 25;
  int mt = half * 25 + mtl;
  int chunk = kt / SUBT, cc = kt - chunk * SUBT;
  int m = mt * 16 + (lane & 15);
  int c = cc * 32 + ((lane >> 4) * 8) + j;
  float val = 0.f;
  if (m < COUT && c < CIN) val = w[((size_t)m * CIN + c) * 9 + chunk];
  dst[el] = __float2bfloat16(val);
}
__global__ __launch_bounds__(256) void k_pack2(const float* __restrict__ w) {
  pack_kmaj<200, 7, 400, 63>(w, g_wp2, 63 * 25 * 512);
}
__global__ __launch_bounds__(256) void k_pack3(const float* __restrict__ w) {
  pack_kmaj<400, 13, 800, 117>(w, g_wp3, 2 * 117 * 25 * 512);
}
// wp4 stays M-major (conv4m path unchanged)
__global__ __launch_bounds__(256) void k_pack4(const float* __restrict__ w) {
  int el = blockIdx.x * 256 + threadIdx.x;
  if (el >= 225 * 512) return;
  int j = el & 7, lane = (el >> 3) & 63, rest = el >> 9;
  int kt = rest % 225;
  int chunk = kt / 25, cc = kt - chunk * 25;
  int m = lane & 15;
  int c = cc * 32 + ((lane >> 4) * 8) + j;
  float val = 0.f;
  if (m < 10 && c < 800) val = w[((size_t)m * 800 + c) * 9 + chunk];
  g_wp4[el] = __float2bfloat16(val);
}

// -------- mask compaction, ORDER-PRESERVING (block scan, 1 block/list) ------
__global__ __launch_bounds__(256) void k_compact(const int* __restrict__ m1,
                                                 const int* __restrict__ m2,
                                                 const int* __restrict__ m3) {
  const int which = blockIdx.x;
  const int* m = which == 0 ? m1 : (which == 1 ? m2 : m3);
  int* lst = which == 0 ? g_list1 : (which == 1 ? g_list2 : g_list3);
  const int n = which == 0 ? 4225 : (which == 1 ? 961 : 225);
  const int per = (n + 255) / 256;
  const int lo = threadIdx.x * per;
  const int hi = lo + per < n ? lo + per : n;
  __shared__ int cnt[256];
  __shared__ int off[256];
  int c = 0;
  for (int i = lo; i < hi; ++i) c += (m[i] != 0);
  cnt[threadIdx.x] = c;
  __syncthreads();
  if (threadIdx.x == 0) {
    int s = 0;
    for (int t = 0; t < 256; ++t) { off[t] = s; s += cnt[t]; }
    g_cnt[which] = s;
  }
  __syncthreads();
  int o = off[threadIdx.x];
  for (int i = lo; i < hi; ++i)
    if (m[i] != 0) lst[o++] = i;
}

// Fill masked-OFF positions with relu(bias) in FRAGMENT layout.
template <int COUT>
__global__ __launch_bounds__(256) void k_fill_off(const int* __restrict__ mask,
                                                  const float* __restrict__ bias,
                                                  bf16* __restrict__ out_t) {
  constexpr int NFULL = (COUT / 32) * 32;
  constexpr int TW = COUT - NFULL;          // 8, 16 or 0
  constexpr int TD = TW ? TW * 16 : 1;      // per-t tail block (elements)
  const int pos = blockIdx.x;
  if (mask[pos] != 0) return;
  bf16* base = out_t + (size_t)pos * 64 * COUT;
  for (int idx = threadIdx.x; idx < 64 * COUT / 8; idx += 256) {
    const int e0 = idx * 8;
    int ch0;
    if (e0 < NFULL * 64) {
      const int cc = e0 >> 11;
      const int r = e0 & 2047;
      const int lq = (r >> 7) & 3;
      ch0 = cc * 32 + lq * 8;
    } else {
      const int r = e0 - NFULL * 64;
      const int r2 = r - (r / TD) * TD;
      const int mq = (TW == 16) ? (r2 >> 7) : 0;
      ch0 = NFULL + mq * 8;
    }
    short8 s;
#pragma unroll
    for (int j = 0; j < 8; ++j) {
      float v = bias[ch0 + j];
      v = v > 0.f ? v : 0.f;
      bf16 h = __float2bfloat16(v);
      s[j] = *reinterpret_cast<short*>(&h);
    }
    *reinterpret_cast<short8*>(base + e0) = s;
  }
}

// zero-fill xt (pad channels 3..7 must be 0)
__global__ __launch_bounds__(256) void k_fill_xt(float* __restrict__ p, int n4) {
  int i = blockIdx.x * 256 + threadIdx.x;
  if (i < n4) reinterpret_cast<float4*>(p)[i] = float4{0.f, 0.f, 0.f, 0.f};
}
// zero-fill d_out (conv4m accumulates with atomics)
__global__ __launch_bounds__(256) void k_zero_out(float* __restrict__ p) {
  int i = blockIdx.x * 256 + threadIdx.x;
  if (i < 64 * 10 * 13 * 13) p[i] = 0.f;
}

// x: [64][3][132][132] fp32 -> xt: [132*132][64][8] bf16 (c innermost, 8-pad)
__global__ __launch_bounds__(256) void k_transpose_x(const float* __restrict__ x,
                                                     bf16* __restrict__ xt) {
  int idx = blockIdx.x * 256 + threadIdx.x;
  constexpr int N = 64 * 3 * 132 * 132;
  if (idx >= N) return;
  int w = idx % 132;
  int t = idx / 132;
  int h = t % 132;
  t /= 132;
  int c = t % 3;
  int b = t / 3;
  xt[((size_t)(h * 132 + w) * 64 + b) * 8 + c] = __float2bfloat16(x[idx]);
}

// -------- shared epilogue: bias + relu + bf16 store in FRAGMENT layout ------
// mcnt: number of valid M-tiles in acc (wave-uniform; guards partial waves).
template <int COUT, int MT>
__device__ __forceinline__ void epilogue_frag(f32x4 (&acc)[MT][4], int pos,
                                              int mt0, int mcnt, int q, int nl,
                                              const float* bias, bf16* out_t) {
  constexpr int NFULL = (COUT / 32) * 32;
  constexpr int TW = COUT - NFULL;  // 8, 16 or 0
  bf16* cell = out_t + (size_t)pos * (COUT * 64);
#pragma unroll
  for (int ms = 0; ms < MT; ++ms) {
    const int T = mt0 + ms;
    const int mbase = T * 16 + q * 4;  // first of this thread's 4 channels
    if (ms < mcnt && mbase < COUT) {
      const float4 bv = *reinterpret_cast<const float4*>(bias + mbase);
#pragma unroll
      for (int t = 0; t < 4; ++t) {
        sh4 s;
#pragma unroll
        for (int r = 0; r < 4; ++r) {
          float vv = acc[ms][t][r] + ((const float*)&bv)[r];
          vv = vv > 0.f ? vv : 0.f;
          bf16 h = __float2bfloat16(vv);
          s[r] = *reinterpret_cast<short*>(&h);
        }
        size_t el;
        if (mbase < NFULL) {
          el = ((size_t)((mbase >> 5) * 4 + t) * 64 +
                (((mbase >> 3) & 3) * 16 + nl)) * 8 + (mbase & 7);
        } else {
          el = (size_t)NFULL * 64 + t * (TW * 16) +
               ((TW == 16) ? (((mbase >> 3) & 1) * 128) : 0) + nl * 8 +
               (mbase & 7);
        }
        *reinterpret_cast<sh4*>(cell + el) = s;
      }
    }
  }
}

// ---------------- L1: division-path sconv (CINW=8 -> shifts), compacted -----
template <int CINW, int COUT, int WIN, int OW, int KTILES, int MT>
__device__ __forceinline__ void sconv_body_div(
    const bf16* __restrict__ in_t, const bf16* __restrict__ wp,
    const float* __restrict__ bias, const int* __restrict__ selh,
    const int* __restrict__ selw, const int* __restrict__ list, int which,
    bf16* __restrict__ out_t) {
  const int bid = blockIdx.x;
  if (bid >= g_cnt[which]) return;
  const int pos = list[bid];
  const int tid = threadIdx.x;
  const int lane = tid & 63;
  const int wv = tid >> 6;
  const int nl = lane & 15;
  const int q = lane >> 4;
  const int mt0 = blockIdx.y * (4 * MT) + wv * MT;
  f32x4 acc[MT][4] = {};
  const int y = pos / OW, xq = pos % OW;
  const int ph = selh[pos] + 2 * y;
  const int pw = selw[pos] + 2 * xq;
  const short8* ap = reinterpret_cast<const short8*>(wp);
#pragma unroll
  for (int kt = 0; kt < KTILES; ++kt) {
    int k = kt * 32 + q * 8;
    int chunk = (int)((unsigned)k / (unsigned)CINW);
    int c = k - chunk * CINW;
    if (chunk > 8) { chunk = 8; c = 0; }
    const int di = (chunk * 342) >> 10;
    const int dj = chunk - di * 3;
    const bf16* bp =
        in_t + ((size_t)((ph + di) * WIN + (pw + dj)) * 64 + nl) * CINW + c;
    short8 Bf[4];
#pragma unroll
    for (int t = 0; t < 4; ++t)
      Bf[t] = *reinterpret_cast<const short8*>(bp + (size_t)t * 16 * CINW);
    short8 Af[MT];
#pragma unroll
    for (int ms = 0; ms < MT; ++ms)
      Af[ms] = ap[((size_t)(mt0 + ms) * KTILES + kt) * 64 + lane];
#pragma unroll
    for (int ms = 0; ms < MT; ++ms)
#pragma unroll
      for (int t = 0; t < 4; ++t)
        acc[ms][t] =
            __builtin_amdgcn_mfma_f32_16x16x32_bf16(Af[ms], Bf[t], acc[ms][t], 0, 0, 0);
  }
  epilogue_frag<COUT, MT>(acc, pos, mt0, MT, q, nl, bias, out_t);
}

// ---- L2/L3: 1024-thr, 16 waves, M EXACT, NPOS=2, K-STEP=64 (tile pairs) ----
// Pair-steps amortize the fixed per-barrier cost (r13: 63 barriers, ~1400cyc
// fixed each; now 32/59). RACE FIX vs r14: stage(cur^1, s+1) is issued AFTER
// barrier(s) -- barrier(s) proves every wave finished compute(s-1)'s
// ds_reads of buffer cur^1 (lgkm-complete before barrier arrival), so the
// 2-buffer overwrite is safe. The wait is a uniform vmcnt(0): at that point
// the ONLY outstanding VMEM is stage(s), issued right after barrier(s-1) and
// covered by a full compute phase (~1600+ cyc > L3 latency).
// Staging per step: 50 A-tiles + 16 B-blocks over 16 waves (wv<2: 4A+1B,
// else 3A+1B). KTILES odd -> final step computes sub 0 only (dup-staged).
template <int CIN, int SUBT, int COUT, int WIN, int OW, int NTILE>
__device__ __forceinline__ void sconv_body_pipe(
    const bf16* __restrict__ in_t, const bf16* __restrict__ wp,
    const float* __restrict__ bias, const int* __restrict__ selh,
    const int* __restrict__ selw, const int* __restrict__ list, int which,
    int bid, int myt, bf16* __restrict__ out_t) {
  constexpr int MT = 4;
  constexpr int KTILES = 9 * SUBT;        // 63 / 117 (odd)
  constexpr int NSTEP = (KTILES + 1) / 2; // 32 / 59
  constexpr int NFC = CIN / 32;           // full input subtiles
  constexpr int TIN = CIN - NFC * 32;     // input tail width (8 or 16)
  __shared__ __align__(16) bf16 Ab[2][2][NTILE * 512];  // 100 KB
  __shared__ __align__(16) bf16 Bb[2][2][2 * 2048];     //  32 KB
  const int cnt = g_cnt[which];
  if (2 * bid >= cnt) return;
  const int p0 = list[2 * bid];
  const int p1 = list[2 * bid + 1 < cnt ? 2 * bid + 1 : cnt - 1];
  const int tid = threadIdx.x;
  const int lane = tid & 63;
  const int wv = tid >> 6;   // 0..15
  const int g = wv & 7;      // consumer slice in position-group
  const int pp = wv >> 3;    // this wave's position (0/1)
  const int tstart = (g == 0) ? 0 : 4 + 3 * (g - 1);  // consumer tiles
  const int tcnt = (g == 0) ? 4 : 3;
  // stage roles: A tiles T in [astart, astart+acnt) of the 50-tile pair-panel
  const int astart = (wv < 2) ? 4 * wv : 3 * wv + 2;
  const int acnt = (wv < 2) ? 4 : 3;
  const int bsub = wv >> 3, bpos = (wv >> 2) & 1, bj = wv & 3;  // B role
  const int nl = lane & 15;
  const int q = lane >> 4;
  const int y0 = p0 / OW, x0 = p0 % OW;
  const int y1 = p1 / OW, x1 = p1 % OW;
  const int ph0 = selh[p0] + 2 * y0, pw0 = selw[p0] + 2 * x0;
  const int ph1 = selh[p1] + 2 * y1, pw1 = selw[p1] + 2 * x1;

  auto cellp = [&](int ph, int pw, int chunk) -> const bf16* {
    const int di = (chunk * 342) >> 10;  // chunk/3
    const int dj = chunk - di * 3;
    return in_t + (size_t)((ph + di) * WIN + (pw + dj)) * (CIN * 64);
  };

  // stage pair-step s into buffer b: acnt A-tile loads + 1 B load per wave.
  auto stage = [&](int b, int s) {
#pragma unroll
    for (int i = 0; i < 4; ++i) {
      if (i < acnt) {
        const int T = astart + i;
        const int sub = (T >= NTILE) ? 1 : 0;
        const int tl = T - sub * NTILE;
        int kts = 2 * s + sub;
        if (kts > KTILES - 1) kts = KTILES - 1;  // dup on final odd step
        const bf16* asrc = wp + ((size_t)kts * NTILE + tl) * 512 + lane * 8;
        __builtin_amdgcn_global_load_lds(
            (const __attribute__((address_space(1))) void*)asrc,
            (__attribute__((address_space(3))) void*)(&Ab[b][sub][tl * 512 +
                                                                  lane * 8]),
            16, 0, 0);
      }
    }
    {
      int kts = 2 * s + bsub;
      if (kts > KTILES - 1) kts = KTILES - 1;
      const int chunk = kts / SUBT;
      const int ccs = kts - chunk * SUBT;
      const bf16* cell = cellp(bpos ? ph1 : ph0, bpos ? pw1 : pw0, chunk);
      int boff;
      if (ccs < NFC) {
        boff = (ccs * 4 + bj) * 512;
      } else {
        int jj = (bj * 512 < TIN * 64) ? bj : 0;  // clamp: dup stage, unread
        boff = NFC * 2048 + jj * 512;
      }
      __builtin_amdgcn_global_load_lds(
          (const __attribute__((address_space(1))) void*)(cell + boff + lane * 8),
          (__attribute__((address_space(3))) void*)(&Bb[b][bsub][bpos * 2048 +
                                                                 bj * 512 +
                                                                 lane * 8]),
          16, 0, 0);
    }
  };

  f32x4 acc[MT][4] = {};

  // Prologue: pair-step 0 in flight.
  stage(0, 0);

  for (int s = 0; s < NSTEP; ++s) {
    const int cur = s & 1;
    __builtin_amdgcn_sched_barrier(0);
    asm volatile("s_waitcnt vmcnt(0)");  // retire stage(s) (issued ~1 compute
    __builtin_amdgcn_sched_barrier(0);   //  phase ago; only VMEM in flight)
    __builtin_amdgcn_s_barrier();        // all waves' stage(s) visible AND
    __builtin_amdgcn_sched_barrier(0);   //  all compute(s-1) reads done
    if (s + 1 < NSTEP) stage(cur ^ 1, s + 1);  // safe: after barrier(s)
    __builtin_amdgcn_sched_barrier(0);

#pragma unroll
    for (int sub = 0; sub < 2; ++sub) {
      const int kts = 2 * s + sub;
      if (kts < KTILES) {
        const int chunk = kts / SUBT;
        const int ccs = kts - chunk * SUBT;
        short8 Af[MT];
#pragma unroll
        for (int ms = 0; ms < MT; ++ms)
          if (ms < tcnt)
            Af[ms] = *reinterpret_cast<const short8*>(
                &Ab[cur][sub][(tstart + ms) * 512 + lane * 8]);
        short8 Bf[4];
        if (ccs != SUBT - 1) {
#pragma unroll
          for (int t = 0; t < 4; ++t)
            Bf[t] = *reinterpret_cast<const short8*>(
                &Bb[cur][sub][pp * 2048 + t * 512 + lane * 8]);
        } else if (TIN == 8) {
#pragma unroll
          for (int t = 0; t < 4; ++t)
            Bf[t] = *reinterpret_cast<const short8*>(
                &Bb[cur][sub][pp * 2048 + t * 128 + nl * 8]);
        } else {
#pragma unroll
          for (int t = 0; t < 4; ++t)
            Bf[t] = *reinterpret_cast<const short8*>(
                &Bb[cur][sub][pp * 2048 + t * 256 + (q & 1) * 128 + nl * 8]);
        }
        __builtin_amdgcn_s_setprio(1);
#pragma unroll
        for (int ms = 0; ms < MT; ++ms)
          if (ms < tcnt)
#pragma unroll
            for (int t = 0; t < 4; ++t)
              acc[ms][t] = __builtin_amdgcn_mfma_f32_16x16x32_bf16(
                  Af[ms], Bf[t], acc[ms][t], 0, 0, 0);
        __builtin_amdgcn_s_setprio(0);
      }
    }
  }
  const int mt0 = myt * NTILE + tstart;
  epilogue_frag<COUT, MT>(acc, pp ? p1 : p0, mt0, tcnt, q, nl, bias, out_t);
}

__global__ __launch_bounds__(256) void k_sconv1(
    const bf16* __restrict__ in_t, const float* __restrict__ bias,
    const int* __restrict__ selh, const int* __restrict__ selw,
    bf16* __restrict__ out_t) {
  sconv_body_div<8, 200, 132, 65, 3, 4>(in_t, g_wp1, bias, selh, selw, g_list1, 0,
                                        out_t);
}
// M=400 exact, K-step=64, grid ceil(961/2)=481.
__global__ __launch_bounds__(1024, 4) void k_sconv2(
    const bf16* __restrict__ in_t, const float* __restrict__ bias,
    const int* __restrict__ selh, const int* __restrict__ selw,
    bf16* __restrict__ out_t) {
  sconv_body_pipe<200, 7, 400, 65, 31, 25>(in_t, g_wp2, bias, selh, selw,
                                           g_list2, 1, blockIdx.x, 0, out_t);
}
// M=800 in two 400-row halves, XCD-aware: xcd=id&7 picks the half; slot
// covers pairs 0..112 per half; grid 232 (slots>=113 return via cnt guard).
__global__ __launch_bounds__(1024, 4) void k_sconv3(
    const bf16* __restrict__ in_t, const float* __restrict__ bias,
    const int* __restrict__ selh, const int* __restrict__ selw,
    bf16* __restrict__ out_t) {
  const int id = blockIdx.x;
  const int xcd = id & 7;
  const int yhalf = xcd >> 2;
  const int slot = (id >> 3) * 4 + (xcd & 3);
  sconv_body_pipe<400, 13, 800, 31, 15, 25>(
      in_t, g_wp3 + (size_t)yhalf * 117 * 25 * 512, bias, selh, selw, g_list3, 2,
      slot, yhalf, out_t);
}

// ---------------- L4: dense 3x3 VALID conv via MFMA, 16-way K-split ---------
__global__ __launch_bounds__(256) void k_conv4m(
    const bf16* __restrict__ in_t,   // [15*15] cells, frag layout, 800 ch
    const float* __restrict__ bias,  // [10] fp32
    float* __restrict__ out) {       // [64][10][13][13] fp32 (pre-zeroed)
  const int pos = blockIdx.x;        // 13*13
  const int y = pos / 13, x = pos % 13;
  const int tid = threadIdx.x;
  const int lane = tid & 63;
  const int wv = tid >> 6;
  const int nl = lane & 15;
  const int q = lane >> 4;
  const int kslice = blockIdx.y * 4 + wv;
  __shared__ f32x4 Racc[4][4][64];
  f32x4 acc[4] = {};
  const short8* ap = reinterpret_cast<const short8*>(g_wp4);
  for (int kt = kslice; kt < 225; kt += 16) {
    const int chunk = kt / 25;  // wave-uniform
    const int cc = kt - chunk * 25;
    const int di = chunk / 3, dj = chunk - di * 3;
    const bf16* cell = in_t + (size_t)((y + di) * 15 + (x + dj)) * (800 * 64);
    short8 A0 = ap[(size_t)kt * 64 + lane];
    short8 Bf[4];
#pragma unroll
    for (int t = 0; t < 4; ++t)
      Bf[t] = *reinterpret_cast<const short8*>(
          cell + ((size_t)(cc * 4 + t) * 64 + lane) * 8);
#pragma unroll
    for (int t = 0; t < 4; ++t)
      acc[t] = __builtin_amdgcn_mfma_f32_16x16x32_bf16(A0, Bf[t], acc[t], 0, 0, 0);
  }
#pragma unroll
  for (int t = 0; t < 4; ++t) Racc[wv][t][lane] = acc[t];
  __syncthreads();
  if (wv == 0) {
    const int rowb = q * 4;
#pragma unroll
    for (int t = 0; t < 4; ++t) {
      f32x4 s = Racc[0][t][lane];
#pragma unroll
      for (int w2 = 1; w2 < 4; ++w2) {
        f32x4 o = Racc[w2][t][lane];
#pragma unroll
        for (int r = 0; r < 4; ++r) s[r] += o[r];
      }
      const int n = t * 16 + nl;
#pragma unroll
      for (int r = 0; r < 4; ++r) {
        const int m = rowb + r;
        if (m < 10) {
          float v = s[r] + (blockIdx.y == 0 ? bias[m] : 0.f);
          atomicAdd(&out[(((size_t)n * 10 + m) * 13 + y) * 13 + x], v);
        }
      }
    }
  }
}

extern "C" void kernel_launch(void* const* d_in, const int* in_sizes, int n_in,
                              void* d_out, int out_size, void* d_ws, size_t ws_size,
                              hipStream_t stream) {
  const float* x  = (const float*)d_in[0];
  const float* w1 = (const float*)d_in[1];
  const float* b1 = (const float*)d_in[2];
  const float* w2 = (const float*)d_in[3];
  const float* b2 = (const float*)d_in[4];
  const float* w3 = (const float*)d_in[5];
  const float* b3 = (const float*)d_in[6];
  const float* w4 = (const float*)d_in[7];
  const float* b4 = (const float*)d_in[8];
  const int* selh1 = (const int*)d_in[9];
  const int* selw1 = (const int*)d_in[10];
  const int* mask1 = (const int*)d_in[11];
  const int* selh2 = (const int*)d_in[12];
  const int* selw2 = (const int*)d_in[13];
  const int* mask2 = (const int*)d_in[14];
  const int* selh3 = (const int*)d_in[15];
  const int* selw3 = (const int*)d_in[16];
  const int* mask3 = (const int*)d_in[17];

  // ws layout (bytes), total == round-5-proven 157,363,200:
  //   o1t bf16 [65*65] cells x 25600B @ 0            (108,160,000 B)
  //   xt  bf16 [132*132][64][8]       @ 108,160,000  (17,842,176 B)
  //   o2t bf16 [31*31] cells x 51200B @ 108,160,000  (49,203,200 B; xt dead)
  //   o3t bf16 [15*15] cells x 102400B@ 0            (23,040,000 B; o1t dead)
  char* ws = (char*)d_ws;
  bf16* o1t = (bf16*)(ws);
  bf16* xt  = (bf16*)(ws + 108160000);
  bf16* o2t = (bf16*)(ws + 108160000);
  bf16* o3t = (bf16*)(ws);

  k_pack1<<<dim3((16 * 3 * 512 + 255) / 256), dim3(256), 0, stream>>>(w1);
  k_pack2<<<dim3((63 * 25 * 512 + 255) / 256), dim3(256), 0, stream>>>(w2);
  k_pack3<<<dim3((2 * 117 * 25 * 512 + 255) / 256), dim3(256), 0, stream>>>(w3);
  k_pack4<<<dim3((225 * 512 + 255) / 256), dim3(256), 0, stream>>>(w4);
  k_compact<<<dim3(3), dim3(256), 0, stream>>>(mask1, mask2, mask3);
  k_fill_xt<<<dim3((2230272 + 255) / 256), dim3(256), 0, stream>>>((float*)xt, 2230272);
  k_transpose_x<<<dim3((64 * 3 * 132 * 132 + 255) / 256), dim3(256), 0, stream>>>(x, xt);
  k_zero_out<<<dim3((64 * 10 * 13 * 13 + 255) / 256), dim3(256), 0, stream>>>(
      (float*)d_out);

  // Masked-off positions: relu(bias) fill (cheap, write-only).
  k_fill_off<200><<<dim3(4225), dim3(256), 0, stream>>>(mask1, b1, o1t);
  // L1 (compacted): M-pad 256, grid (4225, 1)
  k_sconv1<<<dim3(4225, 1), dim3(256), 0, stream>>>(xt, b1, selh1, selw1, o1t);

  k_fill_off<400><<<dim3(961), dim3(256), 0, stream>>>(mask2, b2, o2t);
  // L2: 16-wave blocks, M exact, K-step=64, grid 481 x 1024 threads
  k_sconv2<<<dim3(481, 1), dim3(1024), 0, stream>>>(o1t, b2, selh2, selw2, o2t);

  k_fill_off<800><<<dim3(225), dim3(256), 0, stream>>>(mask3, b3, o3t);
  // L3: 16-wave blocks, M exact, K-step=64, XCD halves, grid 232 x 1024
  k_sconv3<<<dim3(232, 1), dim3(1024), 0, stream>>>(o2t, b3, selh3, selw3, o3t);

  // L4: 16-way K-split, atomic accumulate
  k_conv4m<<<dim3(13 * 13, 4), dim3(256), 0, stream>>>(o3t, b4, (float*)d_out);
}

// Round 16
// 434.374 us; speedup vs baseline: 1.0720x; 1.0720x over previous
//
#include <hip/hip_runtime.h>
#include <hip/hip_bf16.h>

using bf16 = __hip_bfloat16;
using short8 = __attribute__((ext_vector_type(8))) short;
using sh4 = __attribute__((ext_vector_type(4))) short;
using f32x4 = __attribute__((ext_vector_type(4))) float;

// Pre-packed A-operand (weights) in MFMA 16x16x32 frag order, module-scope.
// L1 (div path, M-major): frag (mt,kt) at ((mt*KT + kt)*64+lane)*8.
// L2/L3: K-MAJOR: frag (kt,mtl) at ((kt*32+mtl)*64+lane)*8 -> one kt-panel
//   (32 KB) contiguous for LDS bulk staging. L4 (M-major, 1 mt): unchanged.
__device__ __align__(16) bf16 g_wp1[16 * 3 * 512];    //  48 KB (M 256, KT 3)
__device__ __align__(16) bf16 g_wp2[63 * 32 * 512];   // 2.1 MB K-major (M 512, KT 63)
__device__ __align__(16) bf16 g_wp3[2 * 117 * 32 * 512];  // 7.7 MB 2 halves K-major
__device__ __align__(16) bf16 g_wp4[1 * 225 * 512];   // 231 KB (M 16, KT 225)

// Compacted masked-on position lists (order-preserving -> spatial locality).
__device__ int g_list1[4225];
__device__ int g_list2[961];
__device__ int g_list3[225];
__device__ int g_cnt[3];

// ============================================================================
// Intermediate tensors stored PRE-FRAGMENTED in MFMA B-operand order (1KB
// coalesced wave reads). Cell (position, 64 batch x C ch) element offsets:
//   full subtiles cc < C/32:  el = ((cc*4 + t)*64 + q*16 + nl)*8 + j
//        where ch = cc*32 + q*8 + j, batch = t*16 + nl
//   tail (TW = C mod 32 in {8,16}), after NFULL*64 elements:
//        el = NFULL*64 + t*TW*16 + mq*128 + nl*8 + j   (ch = NFULL + mq*8 + j)
// Cell size = 64*C elements exactly -> ws layout unchanged.
// ============================================================================

// ---------------- weight packs ----------------
__global__ __launch_bounds__(256) void k_pack1(const float* __restrict__ w) {
  int el = blockIdx.x * 256 + threadIdx.x;
  if (el >= 16 * 3 * 512) return;
  int j = el & 7, lane = (el >> 3) & 63, rest = el >> 9;
  int kt = rest % 3, mt = rest / 3;
  int m = mt * 16 + (lane & 15);
  int k = kt * 32 + ((lane >> 4) * 8) + j;
  int chunk = k >> 3, c = k & 7;
  float val = 0.f;
  if (m < 200 && chunk < 9 && c < 3) val = w[((size_t)m * 3 + c) * 9 + chunk];
  g_wp1[el] = __float2bfloat16(val);
}
// K-major pack: tile index ti = el>>9 -> half = ti/(KT*32) (wp3 only),
// kt = (ti%(KT*32))>>5, mtl = ti&31, mt = half*32+mtl.
template <int CIN, int SUBT, int COUT, int KT>
__device__ __forceinline__ void pack_kmaj(const float* __restrict__ w,
                                          bf16* __restrict__ dst, int total) {
  int el = blockIdx.x * 256 + threadIdx.x;
  if (el >= total) return;
  int j = el & 7, lane = (el >> 3) & 63, ti = el >> 9;
  int half = ti / (KT * 32);
  int r2 = ti - half * (KT * 32);
  int kt = r2 >> 5, mtl = r2 & 31;
  int mt = half * 32 + mtl;
  int chunk = kt / SUBT, cc = kt - chunk * SUBT;
  int m = mt * 16 + (lane & 15);
  int c = cc * 32 + ((lane >> 4) * 8) + j;
  float val = 0.f;
  if (m < COUT && c < CIN) val = w[((size_t)m * CIN + c) * 9 + chunk];
  dst[el] = __float2bfloat16(val);
}
__global__ __launch_bounds__(256) void k_pack2(const float* __restrict__ w) {
  pack_kmaj<200, 7, 400, 63>(w, g_wp2, 63 * 32 * 512);
}
__global__ __launch_bounds__(256) void k_pack3(const float* __restrict__ w) {
  pack_kmaj<400, 13, 800, 117>(w, g_wp3, 2 * 117 * 32 * 512);
}
// wp4 stays M-major (conv4m path unchanged)
__global__ __launch_bounds__(256) void k_pack4(const float* __restrict__ w) {
  int el = blockIdx.x * 256 + threadIdx.x;
  if (el >= 225 * 512) return;
  int j = el & 7, lane = (el >> 3) & 63, rest = el >> 9;
  int kt = rest % 225;
  int chunk = kt / 25, cc = kt - chunk * 25;
  int m = lane & 15;
  int c = cc * 32 + ((lane >> 4) * 8) + j;
  float val = 0.f;
  if (m < 10 && c < 800) val = w[((size_t)m * 800 + c) * 9 + chunk];
  g_wp4[el] = __float2bfloat16(val);
}

// -------- mask compaction, ORDER-PRESERVING (block scan, 1 block/list) ------
__global__ __launch_bounds__(256) void k_compact(const int* __restrict__ m1,
                                                 const int* __restrict__ m2,
                                                 const int* __restrict__ m3) {
  const int which = blockIdx.x;
  const int* m = which == 0 ? m1 : (which == 1 ? m2 : m3);
  int* lst = which == 0 ? g_list1 : (which == 1 ? g_list2 : g_list3);
  const int n = which == 0 ? 4225 : (which == 1 ? 961 : 225);
  const int per = (n + 255) / 256;
  const int lo = threadIdx.x * per;
  const int hi = lo + per < n ? lo + per : n;
  __shared__ int cnt[256];
  __shared__ int off[256];
  int c = 0;
  for (int i = lo; i < hi; ++i) c += (m[i] != 0);
  cnt[threadIdx.x] = c;
  __syncthreads();
  if (threadIdx.x == 0) {
    int s = 0;
    for (int t = 0; t < 256; ++t) { off[t] = s; s += cnt[t]; }
    g_cnt[which] = s;
  }
  __syncthreads();
  int o = off[threadIdx.x];
  for (int i = lo; i < hi; ++i)
    if (m[i] != 0) lst[o++] = i;
}

// Fill masked-OFF positions with relu(bias) in FRAGMENT layout.
template <int COUT>
__global__ __launch_bounds__(256) void k_fill_off(const int* __restrict__ mask,
                                                  const float* __restrict__ bias,
                                                  bf16* __restrict__ out_t) {
  constexpr int NFULL = (COUT / 32) * 32;
  constexpr int TW = COUT - NFULL;          // 8, 16 or 0
  constexpr int TD = TW ? TW * 16 : 1;      // per-t tail block (elements)
  const int pos = blockIdx.x;
  if (mask[pos] != 0) return;
  bf16* base = out_t + (size_t)pos * 64 * COUT;
  for (int idx = threadIdx.x; idx < 64 * COUT / 8; idx += 256) {
    const int e0 = idx * 8;
    int ch0;
    if (e0 < NFULL * 64) {
      const int cc = e0 >> 11;
      const int r = e0 & 2047;
      const int lq = (r >> 7) & 3;
      ch0 = cc * 32 + lq * 8;
    } else {
      const int r = e0 - NFULL * 64;
      const int r2 = r - (r / TD) * TD;
      const int mq = (TW == 16) ? (r2 >> 7) : 0;
      ch0 = NFULL + mq * 8;
    }
    short8 s;
#pragma unroll
    for (int j = 0; j < 8; ++j) {
      float v = bias[ch0 + j];
      v = v > 0.f ? v : 0.f;
      bf16 h = __float2bfloat16(v);
      s[j] = *reinterpret_cast<short*>(&h);
    }
    *reinterpret_cast<short8*>(base + e0) = s;
  }
}

// zero-fill xt (pad channels 3..7 must be 0)
__global__ __launch_bounds__(256) void k_fill_xt(float* __restrict__ p, int n4) {
  int i = blockIdx.x * 256 + threadIdx.x;
  if (i < n4) reinterpret_cast<float4*>(p)[i] = float4{0.f, 0.f, 0.f, 0.f};
}
// zero-fill d_out (conv4m accumulates with atomics)
__global__ __launch_bounds__(256) void k_zero_out(float* __restrict__ p) {
  int i = blockIdx.x * 256 + threadIdx.x;
  if (i < 64 * 10 * 13 * 13) p[i] = 0.f;
}

// x: [64][3][132][132] fp32 -> xt: [132*132][64][8] bf16 (c innermost, 8-pad)
__global__ __launch_bounds__(256) void k_transpose_x(const float* __restrict__ x,
                                                     bf16* __restrict__ xt) {
  int idx = blockIdx.x * 256 + threadIdx.x;
  constexpr int N = 64 * 3 * 132 * 132;
  if (idx >= N) return;
  int w = idx % 132;
  int t = idx / 132;
  int h = t % 132;
  t /= 132;
  int c = t % 3;
  int b = t / 3;
  xt[((size_t)(h * 132 + w) * 64 + b) * 8 + c] = __float2bfloat16(x[idx]);
}

// -------- shared epilogue: bias + relu + bf16 store in FRAGMENT layout ------
template <int COUT, int MT>
__device__ __forceinline__ void epilogue_frag(f32x4 (&acc)[MT][4], int pos,
                                              int mt0, int q, int nl,
                                              const float* bias, bf16* out_t) {
  constexpr int NFULL = (COUT / 32) * 32;
  constexpr int TW = COUT - NFULL;  // 8, 16 or 0
  bf16* cell = out_t + (size_t)pos * (COUT * 64);
#pragma unroll
  for (int ms = 0; ms < MT; ++ms) {
    const int T = mt0 + ms;
    const int mbase = T * 16 + q * 4;  // first of this thread's 4 channels
    if (mbase < COUT) {
      const float4 bv = *reinterpret_cast<const float4*>(bias + mbase);
#pragma unroll
      for (int t = 0; t < 4; ++t) {
        sh4 s;
#pragma unroll
        for (int r = 0; r < 4; ++r) {
          float vv = acc[ms][t][r] + ((const float*)&bv)[r];
          vv = vv > 0.f ? vv : 0.f;
          bf16 h = __float2bfloat16(vv);
          s[r] = *reinterpret_cast<short*>(&h);
        }
        size_t el;
        if (mbase < NFULL) {
          el = ((size_t)((mbase >> 5) * 4 + t) * 64 +
                (((mbase >> 3) & 3) * 16 + nl)) * 8 + (mbase & 7);
        } else {
          el = (size_t)NFULL * 64 + t * (TW * 16) +
               ((TW == 16) ? (((mbase >> 3) & 1) * 128) : 0) + nl * 8 +
               (mbase & 7);
        }
        *reinterpret_cast<sh4*>(cell + el) = s;
      }
    }
  }
}

// ---------------- L1: division-path sconv (CINW=8 -> shifts), compacted -----
template <int CINW, int COUT, int WIN, int OW, int KTILES, int MT>
__device__ __forceinline__ void sconv_body_div(
    const bf16* __restrict__ in_t, const bf16* __restrict__ wp,
    const float* __restrict__ bias, const int* __restrict__ selh,
    const int* __restrict__ selw, const int* __restrict__ list, int which,
    bf16* __restrict__ out_t) {
  const int bid = blockIdx.x;
  if (bid >= g_cnt[which]) return;
  const int pos = list[bid];
  const int tid = threadIdx.x;
  const int lane = tid & 63;
  const int wv = tid >> 6;
  const int nl = lane & 15;
  const int q = lane >> 4;
  const int mt0 = blockIdx.y * (4 * MT) + wv * MT;
  f32x4 acc[MT][4] = {};
  const int y = pos / OW, xq = pos % OW;
  const int ph = selh[pos] + 2 * y;
  const int pw = selw[pos] + 2 * xq;
  const short8* ap = reinterpret_cast<const short8*>(wp);
#pragma unroll
  for (int kt = 0; kt < KTILES; ++kt) {
    int k = kt * 32 + q * 8;
    int chunk = (int)((unsigned)k / (unsigned)CINW);
    int c = k - chunk * CINW;
    if (chunk > 8) { chunk = 8; c = 0; }
    const int di = (chunk * 342) >> 10;
    const int dj = chunk - di * 3;
    const bf16* bp =
        in_t + ((size_t)((ph + di) * WIN + (pw + dj)) * 64 + nl) * CINW + c;
    short8 Bf[4];
#pragma unroll
    for (int t = 0; t < 4; ++t)
      Bf[t] = *reinterpret_cast<const short8*>(bp + (size_t)t * 16 * CINW);
    short8 Af[MT];
#pragma unroll
    for (int ms = 0; ms < MT; ++ms)
      Af[ms] = ap[((size_t)(mt0 + ms) * KTILES + kt) * 64 + lane];
#pragma unroll
    for (int ms = 0; ms < MT; ++ms)
#pragma unroll
      for (int t = 0; t < 4; ++t)
        acc[ms][t] =
            __builtin_amdgcn_mfma_f32_16x16x32_bf16(Af[ms], Bf[t], acc[ms][t], 0, 0, 0);
  }
  epilogue_frag<COUT, MT>(acc, pos, mt0, q, nl, bias, out_t);
}

// ---- L2/L3: 1024-thread block, 16 waves = (M-slice, position), NPOS=2 ------
// Wave wv: M-slice = wv&7 (MT=4 -> M=512), position = wv>>3. acc[4][4] = 64
// VGPR/wave -> 4 waves/SIMD resident. LDS triple-buffered: A-panel 32KB + B
// (2 pos) 8KB per buffer = 120KB. Counted vmcnt (T4): each wave stages 2
// A-tiles + (wv<8 ? 1 B-block : 0) per step -> steady-state wait
// vmcnt(3)/vmcnt(2) (wave-uniform branch), vmcnt(0) only at the last step.
// setprio around the MFMA cluster (T5). BEST-MEASURED CONFIG (435.6 us):
// r12 barrier-free, r13 M-exact, r15 K-step-64 all measured null-to-worse.
template <int CIN, int SUBT, int COUT, int WIN, int OW>
__device__ __forceinline__ void sconv_body_pipe(
    const bf16* __restrict__ in_t, const bf16* __restrict__ wp,
    const float* __restrict__ bias, const int* __restrict__ selh,
    const int* __restrict__ selw, const int* __restrict__ list, int which,
    int bid, int myt, bf16* __restrict__ out_t) {
  constexpr int MT = 4;
  constexpr int KTILES = 9 * SUBT;     // 63 / 117 (odd)
  constexpr int NFC = CIN / 32;        // full input subtiles
  constexpr int TIN = CIN - NFC * 32;  // input tail width (8 or 16)
  __shared__ __align__(16) bf16 Ab[3][32 * 512];  // 3 x 32 KB
  __shared__ __align__(16) bf16 Bb[3][2 * 2048];  // 3 x 8 KB (2 positions)
  const int cnt = g_cnt[which];
  if (2 * bid >= cnt) return;
  const int p0 = list[2 * bid];
  const int p1 = list[2 * bid + 1 < cnt ? 2 * bid + 1 : cnt - 1];
  const int tid = threadIdx.x;
  const int lane = tid & 63;
  const int wv = tid >> 6;   // 0..15
  const int msl = wv & 7;    // M-slice (MT=4 tiles each)
  const int pp = wv >> 3;    // this wave's position (0/1)
  const int nl = lane & 15;
  const int q = lane >> 4;
  const int y0 = p0 / OW, x0 = p0 % OW;
  const int y1 = p1 / OW, x1 = p1 % OW;
  const int ph0 = selh[p0] + 2 * y0, pw0 = selw[p0] + 2 * x0;
  const int ph1 = selh[p1] + 2 * y1, pw1 = selw[p1] + 2 * x1;

  auto cellp = [&](int ph, int pw, int chunk) -> const bf16* {
    const int di = (chunk * 342) >> 10;  // chunk/3
    const int dj = chunk - di * 3;
    return in_t + (size_t)((ph + di) * WIN + (pw + dj)) * (CIN * 64);
  };

  // stage-stream state (runs 2 steps ahead of the consumer)
  int scc = 0, sch = 0;
  const bf16* scell0 = cellp(ph0, pw0, 0);
  const bf16* scell1 = cellp(ph1, pw1, 0);

  // stage panel+B for stage-stream kt into buffer b.
  // Per wave: 2 A-tile loads + (wv<8 ? 1 B load : 0).
  auto stage = [&](int b) {
    const int kt = sch * SUBT + scc;
    const bf16* asrc = wp + ((size_t)kt * 32 + wv * 2) * 512 + lane * 8;
#pragma unroll
    for (int i = 0; i < 2; ++i) {
      __builtin_amdgcn_global_load_lds(
          (const __attribute__((address_space(1))) void*)(asrc + (size_t)i * 512),
          (__attribute__((address_space(3))) void*)(&Ab[b][(wv * 2 + i) * 512 +
                                                           lane * 8]),
          16, 0, 0);
    }
    if (wv < 8) {
      const int j = wv & 3;
      const bf16* cell = (wv >> 2) ? scell1 : scell0;
      int boff;
      if (scc < NFC) {
        boff = (scc * 4 + j) * 512;
      } else {
        int jj = (j * 512 < TIN * 64) ? j : 0;  // clamp: dup stage, unread
        boff = NFC * 2048 + jj * 512;
      }
      __builtin_amdgcn_global_load_lds(
          (const __attribute__((address_space(1))) void*)(cell + boff + lane * 8),
          (__attribute__((address_space(3))) void*)(&Bb[b][(wv >> 2) * 2048 +
                                                           j * 512 + lane * 8]),
          16, 0, 0);
    }
    // advance stage stream
    if (++scc == SUBT) {
      scc = 0;
      if (++sch > 8) sch = 8;  // clamp (last advance unused)
      scell0 = cellp(ph0, pw0, sch);
      scell1 = cellp(ph1, pw1, sch);
    }
  };

  f32x4 acc[MT][4] = {};

  // Prologue: panels 0 and 1 in flight.
  stage(0);
  stage(1);

  int buf = 0, ccC = 0;
  for (int kt = 0; kt < KTILES; ++kt) {
    __builtin_amdgcn_sched_barrier(0);
    if (kt == KTILES - 1) {
      asm volatile("s_waitcnt vmcnt(0)");
    } else if (wv < 8) {
      asm volatile("s_waitcnt vmcnt(3)");
    } else {
      asm volatile("s_waitcnt vmcnt(2)");
    }
    __builtin_amdgcn_sched_barrier(0);
    __builtin_amdgcn_s_barrier();
    __builtin_amdgcn_sched_barrier(0);

    short8 Af[MT];
#pragma unroll
    for (int ms = 0; ms < MT; ++ms)
      Af[ms] = *reinterpret_cast<const short8*>(
          &Ab[buf][(msl * 4 + ms) * 512 + lane * 8]);
    short8 Bf[4];
    if (ccC != SUBT - 1) {
#pragma unroll
      for (int t = 0; t < 4; ++t)
        Bf[t] = *reinterpret_cast<const short8*>(
            &Bb[buf][pp * 2048 + t * 512 + lane * 8]);
    } else if (TIN == 8) {
#pragma unroll
      for (int t = 0; t < 4; ++t)
        Bf[t] = *reinterpret_cast<const short8*>(
            &Bb[buf][pp * 2048 + t * 128 + nl * 8]);
    } else {
#pragma unroll
      for (int t = 0; t < 4; ++t)
        Bf[t] = *reinterpret_cast<const short8*>(
            &Bb[buf][pp * 2048 + t * 256 + (q & 1) * 128 + nl * 8]);
    }
    __builtin_amdgcn_s_setprio(1);
#pragma unroll
    for (int ms = 0; ms < MT; ++ms)
#pragma unroll
      for (int t = 0; t < 4; ++t)
        acc[ms][t] = __builtin_amdgcn_mfma_f32_16x16x32_bf16(Af[ms], Bf[t],
                                                             acc[ms][t], 0, 0, 0);
    __builtin_amdgcn_s_setprio(0);
    __builtin_amdgcn_sched_barrier(0);
    if (kt + 2 < KTILES) {
      int sb = buf + 2;
      if (sb >= 3) sb -= 3;
      stage(sb);
    }
    if (++ccC == SUBT) ccC = 0;
    if (++buf == 3) buf = 0;
  }
  const int mt0 = myt * 32 + msl * MT;
  epilogue_frag<COUT, MT>(acc, pp ? p1 : p0, mt0, q, nl, bias, out_t);
}

__global__ __launch_bounds__(256) void k_sconv1(
    const bf16* __restrict__ in_t, const float* __restrict__ bias,
    const int* __restrict__ selh, const int* __restrict__ selw,
    bf16* __restrict__ out_t) {
  sconv_body_div<8, 200, 132, 65, 3, 4>(in_t, g_wp1, bias, selh, selw, g_list1, 0,
                                        out_t);
}
// M=512, 16 waves (8 M-slices x 2 positions), grid ceil(961/2)=481.
__global__ __launch_bounds__(1024, 4) void k_sconv2(
    const bf16* __restrict__ in_t, const float* __restrict__ bias,
    const int* __restrict__ selh, const int* __restrict__ selw,
    bf16* __restrict__ out_t) {
  sconv_body_pipe<200, 7, 400, 65, 31>(in_t, g_wp2, bias, selh, selw, g_list2, 1,
                                       blockIdx.x, 0, out_t);
}
// M=1024 in two halves, XCD-aware: xcd=id&7 picks the half (each XCD's L2
// holds one 3.85MB half-pack); slot covers pairs 0..112 per half; grid 232
// -> single dispatch round. Guarded for slot>=113.
__global__ __launch_bounds__(1024, 4) void k_sconv3(
    const bf16* __restrict__ in_t, const float* __restrict__ bias,
    const int* __restrict__ selh, const int* __restrict__ selw,
    bf16* __restrict__ out_t) {
  const int id = blockIdx.x;
  const int xcd = id & 7;
  const int yhalf = xcd >> 2;
  const int slot = (id >> 3) * 4 + (xcd & 3);
  sconv_body_pipe<400, 13, 800, 31, 15>(in_t, g_wp3 + (size_t)yhalf * 117 * 32 * 512,
                                        bias, selh, selw, g_list3, 2, slot, yhalf,
                                        out_t);
}

// ---------------- L4: dense 3x3 VALID conv via MFMA, 16-way K-split ---------
__global__ __launch_bounds__(256) void k_conv4m(
    const bf16* __restrict__ in_t,   // [15*15] cells, frag layout, 800 ch
    const float* __restrict__ bias,  // [10] fp32
    float* __restrict__ out) {       // [64][10][13][13] fp32 (pre-zeroed)
  const int pos = blockIdx.x;        // 13*13
  const int y = pos / 13, x = pos % 13;
  const int tid = threadIdx.x;
  const int lane = tid & 63;
  const int wv = tid >> 6;
  const int nl = lane & 15;
  const int q = lane >> 4;
  const int kslice = blockIdx.y * 4 + wv;
  __shared__ f32x4 Racc[4][4][64];
  f32x4 acc[4] = {};
  const short8* ap = reinterpret_cast<const short8*>(g_wp4);
  for (int kt = kslice; kt < 225; kt += 16) {
    const int chunk = kt / 25;  // wave-uniform
    const int cc = kt - chunk * 25;
    const int di = chunk / 3, dj = chunk - di * 3;
    const bf16* cell = in_t + (size_t)((y + di) * 15 + (x + dj)) * (800 * 64);
    short8 A0 = ap[(size_t)kt * 64 + lane];
    short8 Bf[4];
#pragma unroll
    for (int t = 0; t < 4; ++t)
      Bf[t] = *reinterpret_cast<const short8*>(
          cell + ((size_t)(cc * 4 + t) * 64 + lane) * 8);
#pragma unroll
    for (int t = 0; t < 4; ++t)
      acc[t] = __builtin_amdgcn_mfma_f32_16x16x32_bf16(A0, Bf[t], acc[t], 0, 0, 0);
  }
#pragma unroll
  for (int t = 0; t < 4; ++t) Racc[wv][t][lane] = acc[t];
  __syncthreads();
  if (wv == 0) {
    const int rowb = q * 4;
#pragma unroll
    for (int t = 0; t < 4; ++t) {
      f32x4 s = Racc[0][t][lane];
#pragma unroll
      for (int w2 = 1; w2 < 4; ++w2) {
        f32x4 o = Racc[w2][t][lane];
#pragma unroll
        for (int r = 0; r < 4; ++r) s[r] += o[r];
      }
      const int n = t * 16 + nl;
#pragma unroll
      for (int r = 0; r < 4; ++r) {
        const int m = rowb + r;
        if (m < 10) {
          float v = s[r] + (blockIdx.y == 0 ? bias[m] : 0.f);
          atomicAdd(&out[(((size_t)n * 10 + m) * 13 + y) * 13 + x], v);
        }
      }
    }
  }
}

extern "C" void kernel_launch(void* const* d_in, const int* in_sizes, int n_in,
                              void* d_out, int out_size, void* d_ws, size_t ws_size,
                              hipStream_t stream) {
  const float* x  = (const float*)d_in[0];
  const float* w1 = (const float*)d_in[1];
  const float* b1 = (const float*)d_in[2];
  const float* w2 = (const float*)d_in[3];
  const float* b2 = (const float*)d_in[4];
  const float* w3 = (const float*)d_in[5];
  const float* b3 = (const float*)d_in[6];
  const float* w4 = (const float*)d_in[7];
  const float* b4 = (const float*)d_in[8];
  const int* selh1 = (const int*)d_in[9];
  const int* selw1 = (const int*)d_in[10];
  const int* mask1 = (const int*)d_in[11];
  const int* selh2 = (const int*)d_in[12];
  const int* selw2 = (const int*)d_in[13];
  const int* mask2 = (const int*)d_in[14];
  const int* selh3 = (const int*)d_in[15];
  const int* selw3 = (const int*)d_in[16];
  const int* mask3 = (const int*)d_in[17];

  // ws layout (bytes), total == round-5-proven 157,363,200:
  //   o1t bf16 [65*65] cells x 25600B @ 0            (108,160,000 B)
  //   xt  bf16 [132*132][64][8]       @ 108,160,000  (17,842,176 B)
  //   o2t bf16 [31*31] cells x 51200B @ 108,160,000  (49,203,200 B; xt dead)
  //   o3t bf16 [15*15] cells x 102400B@ 0            (23,040,000 B; o1t dead)
  char* ws = (char*)d_ws;
  bf16* o1t = (bf16*)(ws);
  bf16* xt  = (bf16*)(ws + 108160000);
  bf16* o2t = (bf16*)(ws + 108160000);
  bf16* o3t = (bf16*)(ws);

  k_pack1<<<dim3((16 * 3 * 512 + 255) / 256), dim3(256), 0, stream>>>(w1);
  k_pack2<<<dim3((63 * 32 * 512 + 255) / 256), dim3(256), 0, stream>>>(w2);
  k_pack3<<<dim3((2 * 117 * 32 * 512 + 255) / 256), dim3(256), 0, stream>>>(w3);
  k_pack4<<<dim3((225 * 512 + 255) / 256), dim3(256), 0, stream>>>(w4);
  k_compact<<<dim3(3), dim3(256), 0, stream>>>(mask1, mask2, mask3);
  k_fill_xt<<<dim3((2230272 + 255) / 256), dim3(256), 0, stream>>>((float*)xt, 2230272);
  k_transpose_x<<<dim3((64 * 3 * 132 * 132 + 255) / 256), dim3(256), 0, stream>>>(x, xt);
  k_zero_out<<<dim3((64 * 10 * 13 * 13 + 255) / 256), dim3(256), 0, stream>>>(
      (float*)d_out);

  // Masked-off positions: relu(bias) fill (cheap, write-only).
  k_fill_off<200><<<dim3(4225), dim3(256), 0, stream>>>(mask1, b1, o1t);
  // L1 (compacted): M-pad 256, grid (4225, 1)
  k_sconv1<<<dim3(4225, 1), dim3(256), 0, stream>>>(xt, b1, selh1, selw1, o1t);

  k_fill_off<400><<<dim3(961), dim3(256), 0, stream>>>(mask2, b2, o2t);
  // L2: 16-wave blocks, NPOS=2, grid 481 x 1024 threads
  k_sconv2<<<dim3(481, 1), dim3(1024), 0, stream>>>(o1t, b2, selh2, selw2, o2t);

  k_fill_off<800><<<dim3(225), dim3(256), 0, stream>>>(mask3, b3, o3t);
  // L3: 16-wave blocks, NPOS=2, XCD-aware halves, grid 232 x 1024 threads
  k_sconv3<<<dim3(232, 1), dim3(1024), 0, stream>>>(o2t, b3, selh3, selw3, o3t);

  // L4: 16-way K-split, atomic accumulate
  k_conv4m<<<dim3(13 * 13, 4), dim3(256), 0, stream>>>(o3t, b4, (float*)d_out);
}